// Round 1
// baseline (2361.847 us; speedup 1.0000x reference)
//
#include <hip/hip_runtime.h>

#define NN 100000
#define EE 3200000
#define F_IN 128
#define HDIM 64
#define NUM_GRAPHS 256

// --- degree histogram: deg[dst] += 1 per edge ---
__global__ void deg_kernel(const int* __restrict__ dst, float* __restrict__ deg, int e) {
    int i = blockIdx.x * blockDim.x + threadIdx.x;
    if (i < e) atomicAdd(&deg[dst[i]], 1.0f);
}

// --- dinv[n] = rsqrt(deg[n] + 1)  (+1 = self-loop; always > 0) ---
__global__ void rsqrt_kernel(float* __restrict__ deg, int n) {
    int i = blockIdx.x * blockDim.x + threadIdx.x;
    if (i < n) deg[i] = rsqrtf(deg[i] + 1.0f);
}

// --- small GEMM: out[n,64] = A[n,K] @ W[K,64], W staged in LDS ---
// one wave per row; lane = output column; float4 broadcast loads of A row
template<int K>
__global__ void gemm_kernel(const float* __restrict__ A, const float* __restrict__ W,
                            float* __restrict__ out, int n) {
    __shared__ float Ws[K * 64];
    for (int i = threadIdx.x; i < K * 64; i += blockDim.x) Ws[i] = W[i];
    __syncthreads();
    int row  = blockIdx.x * (blockDim.x >> 6) + (threadIdx.x >> 6);
    int lane = threadIdx.x & 63;
    if (row >= n) return;
    const float4* ar = reinterpret_cast<const float4*>(A + (size_t)row * K);
    float acc = 0.f;
#pragma unroll
    for (int k4 = 0; k4 < K / 4; ++k4) {
        float4 av = ar[k4];
        acc = fmaf(av.x, Ws[(k4 * 4 + 0) * 64 + lane], acc);
        acc = fmaf(av.y, Ws[(k4 * 4 + 1) * 64 + lane], acc);
        acc = fmaf(av.z, Ws[(k4 * 4 + 2) * 64 + lane], acc);
        acc = fmaf(av.w, Ws[(k4 * 4 + 3) * 64 + lane], acc);
    }
    out[(size_t)row * 64 + lane] = acc;
}

// --- edge scatter: one wave per edge, lane = feature col ---
// agg[dst] += hw[src] * dinv[src]*dinv[dst]
__global__ void scatter_kernel(const int* __restrict__ src, const int* __restrict__ dst,
                               const float* __restrict__ dinv, const float* __restrict__ hw,
                               float* __restrict__ agg, int e) {
    int w = (blockIdx.x * blockDim.x + threadIdx.x) >> 6;
    int lane = threadIdx.x & 63;
    if (w >= e) return;
    int s = src[w], d = dst[w];
    float nrm = dinv[s] * dinv[d];
    atomicAdd(&agg[(size_t)d * 64 + lane], hw[(size_t)s * 64 + lane] * nrm);
}

// --- fused: v = relu(agg + hw*dinv^2 (self-loop) + b); optionally store h,
// optionally accumulate mean-pool sums ---
template<bool STORE, bool POOL>
__global__ void fuse_kernel(float* __restrict__ agg, const float* __restrict__ hw,
                            const float* __restrict__ dinv, const float* __restrict__ b,
                            const int* __restrict__ batch,
                            float* __restrict__ pooled, float* __restrict__ cnt, int n) {
    int w = (blockIdx.x * blockDim.x + threadIdx.x) >> 6;
    int lane = threadIdx.x & 63;
    if (w >= n) return;
    float di = dinv[w];
    float v = agg[(size_t)w * 64 + lane] + hw[(size_t)w * 64 + lane] * di * di + b[lane];
    v = fmaxf(v, 0.f);
    if (STORE) agg[(size_t)w * 64 + lane] = v;
    if (POOL) {
        int g = batch[w];
        atomicAdd(&pooled[(size_t)g * 64 + lane], v);
        if (lane == 0) atomicAdd(&cnt[g], 1.0f);
    }
}

// --- per-graph: out[g] = dot(pooled[g]/max(cnt,1), Wfc) + bfc ---
__global__ void final_kernel(const float* __restrict__ pooled, const float* __restrict__ cnt,
                             const float* __restrict__ Wfc, const float* __restrict__ bfc,
                             float* __restrict__ out) {
    int g = blockIdx.x;
    int lane = threadIdx.x;  // block = 64 = 1 wave
    float c = fmaxf(cnt[g], 1.0f);
    float v = (pooled[(size_t)g * 64 + lane] / c) * Wfc[lane];
#pragma unroll
    for (int off = 32; off; off >>= 1) v += __shfl_down(v, off);
    if (lane == 0) out[g] = v + bfc[0];
}

extern "C" void kernel_launch(void* const* d_in, const int* in_sizes, int n_in,
                              void* d_out, int out_size, void* d_ws, size_t ws_size,
                              hipStream_t stream) {
    const float* x    = (const float*)d_in[0];
    const int*   ei   = (const int*)d_in[1];
    const int*   batch= (const int*)d_in[2];
    const float* W1   = (const float*)d_in[3];
    const float* b1   = (const float*)d_in[4];
    const float* W2   = (const float*)d_in[5];
    const float* b2   = (const float*)d_in[6];
    const float* Wfc  = (const float*)d_in[7];
    const float* bfc  = (const float*)d_in[8];
    float* out = (float*)d_out;

    const int n = in_sizes[0] / F_IN;   // 100000
    const int e = in_sizes[1] / 2;      // 3200000
    const int* srcp = ei;        // edge_index[0]
    const int* dstp = ei + e;    // edge_index[1]

    // workspace layout (floats): dinv | hw(N*64) | agg(N*64) | pooled(256*64) | cnt(256)
    float* ws   = (float*)d_ws;
    size_t nAl  = ((size_t)n + 255) & ~(size_t)255;
    float* dinv = ws;
    float* hw   = ws + nAl;
    float* agg  = hw + (size_t)n * 64;
    float* pooled = agg + (size_t)n * 64;
    float* cnt  = pooled + (size_t)NUM_GRAPHS * 64;

    // 1. degrees -> dinv
    hipMemsetAsync(dinv, 0, (size_t)n * sizeof(float), stream);
    deg_kernel<<<(e + 255) / 256, 256, 0, stream>>>(dstp, dinv, e);
    rsqrt_kernel<<<(n + 255) / 256, 256, 0, stream>>>(dinv, n);

    // 2. layer 1
    gemm_kernel<F_IN><<<(n + 3) / 4, 256, 0, stream>>>(x, W1, hw, n);
    hipMemsetAsync(agg, 0, (size_t)n * 64 * sizeof(float), stream);
    scatter_kernel<<<(e + 3) / 4, 256, 0, stream>>>(srcp, dstp, dinv, hw, agg, e);
    fuse_kernel<true, false><<<(n + 3) / 4, 256, 0, stream>>>(agg, hw, dinv, b1, batch,
                                                              nullptr, nullptr, n);

    // 3. layer 2 (h1 lives in agg; gemm writes hw, then agg is cleared for re-use)
    gemm_kernel<HDIM><<<(n + 3) / 4, 256, 0, stream>>>(agg, W2, hw, n);
    hipMemsetAsync(agg, 0, (size_t)n * 64 * sizeof(float), stream);
    hipMemsetAsync(pooled, 0, ((size_t)NUM_GRAPHS * 64 + NUM_GRAPHS) * sizeof(float), stream);
    scatter_kernel<<<(e + 3) / 4, 256, 0, stream>>>(srcp, dstp, dinv, hw, agg, e);
    fuse_kernel<false, true><<<(n + 3) / 4, 256, 0, stream>>>(agg, hw, dinv, b2, batch,
                                                              pooled, cnt, n);

    // 4. head
    final_kernel<<<NUM_GRAPHS, 64, 0, stream>>>(pooled, cnt, Wfc, bfc, out);
}

// Round 2
// 1544.965 us; speedup vs baseline: 1.5287x; 1.5287x over previous
//
#include <hip/hip_runtime.h>

#define F_IN 128
#define HDIM 64
#define NUM_GRAPHS 256
#define SCAN_BLK 256
#define SCAN_CHUNK 2048   // 256 threads x 8 elems

// --- degree histogram (int): deg[dst] += 1 per edge ---
__global__ void hist_kernel(const int* __restrict__ dst, int* __restrict__ deg, int e) {
    int i = blockIdx.x * blockDim.x + threadIdx.x;
    if (i < e) atomicAdd(&deg[dst[i]], 1);
}

// --- scan pass A: per-block sums of deg over SCAN_CHUNK elems ---
__global__ void scan_partial(const int* __restrict__ deg, int* __restrict__ partial, int n) {
    __shared__ int lds[SCAN_BLK];
    int b = blockIdx.x, t = threadIdx.x;
    int base = b * SCAN_CHUNK + t * 8;
    int s = 0;
#pragma unroll
    for (int j = 0; j < 8; ++j) { int idx = base + j; if (idx < n) s += deg[idx]; }
    lds[t] = s; __syncthreads();
    for (int off = SCAN_BLK / 2; off; off >>= 1) {
        if (t < off) lds[t] += lds[t + off];
        __syncthreads();
    }
    if (t == 0) partial[b] = lds[0];
}

// --- scan pass B: serial exclusive scan of block sums (nb ~ 49), write off[n] ---
__global__ void scan_spine(int* __restrict__ partial, int nb, int* __restrict__ off_end) {
    if (threadIdx.x == 0 && blockIdx.x == 0) {
        int run = 0;
        for (int i = 0; i < nb; ++i) { int v = partial[i]; partial[i] = run; run += v; }
        off_end[0] = run;
    }
}

// --- scan pass C: final exclusive scan; writes off[], cursor[], dinv[] ---
__global__ void scan_final(const int* __restrict__ deg, const int* __restrict__ partial,
                           int* __restrict__ off, int* __restrict__ cursor,
                           float* __restrict__ dinv, int n) {
    __shared__ int lds[SCAN_BLK];
    int b = blockIdx.x, t = threadIdx.x;
    int base = b * SCAN_CHUNK + t * 8;
    int v[8]; int s = 0;
#pragma unroll
    for (int j = 0; j < 8; ++j) { int idx = base + j; v[j] = (idx < n) ? deg[idx] : 0; s += v[j]; }
    lds[t] = s; __syncthreads();
    // inclusive Hillis-Steele over 256 entries
    for (int o = 1; o < SCAN_BLK; o <<= 1) {
        int y = (t >= o) ? lds[t - o] : 0;
        __syncthreads();
        if (t >= o) lds[t] += y;
        __syncthreads();
    }
    int run = partial[b] + lds[t] - s;   // exclusive prefix for this thread's chunk
#pragma unroll
    for (int j = 0; j < 8; ++j) {
        int idx = base + j;
        if (idx < n) {
            off[idx] = run; cursor[idx] = run;
            dinv[idx] = rsqrtf((float)v[j] + 1.0f);   // +1 self-loop
        }
        run += v[j];
    }
}

// --- CSR fill: csr[cursor[dst]++] = src ---
__global__ void fill_kernel(const int* __restrict__ src, const int* __restrict__ dst,
                            int* __restrict__ cursor, int* __restrict__ csr, int e) {
    int i = blockIdx.x * blockDim.x + threadIdx.x;
    if (i < e) {
        int pos = atomicAdd(&cursor[dst[i]], 1);
        csr[pos] = src[i];
    }
}

// --- small GEMM: out[n,64] = (A[n,K] @ W[K,64]) * dinv[row]  (pre-scaled rows) ---
template<int K>
__global__ void gemm_kernel(const float* __restrict__ A, const float* __restrict__ W,
                            const float* __restrict__ dinv, float* __restrict__ out, int n) {
    __shared__ float Ws[K * 64];
    for (int i = threadIdx.x; i < K * 64; i += blockDim.x) Ws[i] = W[i];
    __syncthreads();
    int row  = blockIdx.x * (blockDim.x >> 6) + (threadIdx.x >> 6);
    int lane = threadIdx.x & 63;
    if (row >= n) return;
    const float4* ar = reinterpret_cast<const float4*>(A + (size_t)row * K);
    float acc = 0.f;
#pragma unroll
    for (int k4 = 0; k4 < K / 4; ++k4) {
        float4 av = ar[k4];
        acc = fmaf(av.x, Ws[(k4 * 4 + 0) * 64 + lane], acc);
        acc = fmaf(av.y, Ws[(k4 * 4 + 1) * 64 + lane], acc);
        acc = fmaf(av.z, Ws[(k4 * 4 + 2) * 64 + lane], acc);
        acc = fmaf(av.w, Ws[(k4 * 4 + 3) * 64 + lane], acc);
    }
    out[(size_t)row * 64 + lane] = acc * dinv[row];
}

// --- gather aggregation: one wave per dst node, lane = feature ---
// v = relu((sum_{s in N(d)} hws[s] + hws[d]) * dinv[d] + b)
// POOL=false: store h1.  POOL=true: atomic mean-pool accumulation, no store.
template<bool POOL>
__global__ void gather_kernel(const int* __restrict__ off, const int* __restrict__ csr,
                              const float* __restrict__ hws, const float* __restrict__ dinv,
                              const float* __restrict__ b, const int* __restrict__ batch,
                              float* __restrict__ hout, float* __restrict__ pooled,
                              float* __restrict__ cnt, int n) {
    int d = blockIdx.x * (blockDim.x >> 6) + (threadIdx.x >> 6);
    int lane = threadIdx.x & 63;
    if (d >= n) return;
    int beg = off[d], end = off[d + 1];
    float acc0 = 0.f, acc1 = 0.f;
    int i = beg;
    for (; i + 2 <= end; i += 2) {
        int s0 = csr[i], s1 = csr[i + 1];
        acc0 += hws[(size_t)s0 * 64 + lane];
        acc1 += hws[(size_t)s1 * 64 + lane];
    }
    if (i < end) acc0 += hws[(size_t)csr[i] * 64 + lane];
    float v = (acc0 + acc1 + hws[(size_t)d * 64 + lane]) * dinv[d] + b[lane];
    v = fmaxf(v, 0.f);
    if (POOL) {
        int g = batch[d];
        atomicAdd(&pooled[(size_t)g * 64 + lane], v);
        if (lane == 0) atomicAdd(&cnt[g], 1.0f);
    } else {
        hout[(size_t)d * 64 + lane] = v;
    }
}

// --- per-graph head: out[g] = dot(pooled[g]/max(cnt,1), Wfc) + bfc ---
__global__ void final_kernel(const float* __restrict__ pooled, const float* __restrict__ cnt,
                             const float* __restrict__ Wfc, const float* __restrict__ bfc,
                             float* __restrict__ out) {
    int g = blockIdx.x;
    int lane = threadIdx.x;  // block = 64 = 1 wave
    float c = fmaxf(cnt[g], 1.0f);
    float v = (pooled[(size_t)g * 64 + lane] / c) * Wfc[lane];
#pragma unroll
    for (int off = 32; off; off >>= 1) v += __shfl_down(v, off);
    if (lane == 0) out[g] = v + bfc[0];
}

extern "C" void kernel_launch(void* const* d_in, const int* in_sizes, int n_in,
                              void* d_out, int out_size, void* d_ws, size_t ws_size,
                              hipStream_t stream) {
    const float* x    = (const float*)d_in[0];
    const int*   ei   = (const int*)d_in[1];
    const int*   batch= (const int*)d_in[2];
    const float* W1   = (const float*)d_in[3];
    const float* b1   = (const float*)d_in[4];
    const float* W2   = (const float*)d_in[5];
    const float* b2   = (const float*)d_in[6];
    const float* Wfc  = (const float*)d_in[7];
    const float* bfc  = (const float*)d_in[8];
    float* out = (float*)d_out;

    const int n = in_sizes[0] / F_IN;   // 100000
    const int e = in_sizes[1] / 2;      // 3200000
    const int* srcp = ei;        // edge_index[0]
    const int* dstp = ei + e;    // edge_index[1]

    // workspace layout (4-byte units, 256-elem aligned blocks):
    size_t nAl = ((size_t)n + 256) & ~(size_t)255;   // room for n+1
    int*   deg     = (int*)d_ws;                 // n
    int*   off     = deg + nAl;                  // n+1
    int*   cursor  = off + nAl;                  // n
    int*   partial = cursor + nAl;               // 64
    float* dinv    = (float*)(partial + 256);    // n
    int*   csr     = (int*)(dinv + nAl);         // e
    size_t eAl     = ((size_t)e + 255) & ~(size_t)255;
    float* hws     = (float*)(csr + eAl);        // n*64
    float* h1      = hws + (size_t)n * 64;       // n*64
    float* pooled  = h1 + (size_t)n * 64;        // 256*64
    float* cnt     = pooled + (size_t)NUM_GRAPHS * 64;  // 256

    const int nb = (n + SCAN_CHUNK - 1) / SCAN_CHUNK;   // scan blocks (49)

    // 1. CSR build
    hipMemsetAsync(deg, 0, (size_t)n * sizeof(int), stream);
    hist_kernel<<<(e + 255) / 256, 256, 0, stream>>>(dstp, deg, e);
    scan_partial<<<nb, SCAN_BLK, 0, stream>>>(deg, partial, n);
    scan_spine<<<1, 64, 0, stream>>>(partial, nb, &off[n]);
    scan_final<<<nb, SCAN_BLK, 0, stream>>>(deg, partial, off, cursor, dinv, n);
    fill_kernel<<<(e + 255) / 256, 256, 0, stream>>>(srcp, dstp, cursor, csr, e);

    // 2. layer 1: hws = (x@W1)*dinv ; h1 = relu(gather + self + b1)
    gemm_kernel<F_IN><<<(n + 3) / 4, 256, 0, stream>>>(x, W1, dinv, hws, n);
    gather_kernel<false><<<(n + 3) / 4, 256, 0, stream>>>(off, csr, hws, dinv, b1, batch,
                                                          h1, nullptr, nullptr, n);

    // 3. layer 2: hws = (h1@W2)*dinv ; pooled += relu(gather + self + b2)
    gemm_kernel<HDIM><<<(n + 3) / 4, 256, 0, stream>>>(h1, W2, dinv, hws, n);
    hipMemsetAsync(pooled, 0, ((size_t)NUM_GRAPHS * 64 + NUM_GRAPHS) * sizeof(float), stream);
    gather_kernel<true><<<(n + 3) / 4, 256, 0, stream>>>(off, csr, hws, dinv, b2, batch,
                                                         nullptr, pooled, cnt, n);

    // 4. head
    final_kernel<<<NUM_GRAPHS, 64, 0, stream>>>(pooled, cnt, Wfc, bfc, out);
}

// Round 4
// 1252.707 us; speedup vs baseline: 1.8854x; 1.2333x over previous
//
#include <hip/hip_runtime.h>

#define F_IN 128
#define HDIM 64
#define NUM_GRAPHS 256
#define SCAN_BLK 256
#define SCAN_CHUNK 2048   // 256 threads x 8 elems

// --- degree histogram (int): deg[dst] += 1 per edge ---
__global__ void hist_kernel(const int* __restrict__ dst, int* __restrict__ deg, int e) {
    int i = blockIdx.x * blockDim.x + threadIdx.x;
    if (i < e) atomicAdd(&deg[dst[i]], 1);
}

// --- scan pass A: per-block sums of deg over SCAN_CHUNK elems ---
__global__ void scan_partial(const int* __restrict__ deg, int* __restrict__ partial, int n) {
    __shared__ int lds[SCAN_BLK];
    int b = blockIdx.x, t = threadIdx.x;
    int base = b * SCAN_CHUNK + t * 8;
    int s = 0;
#pragma unroll
    for (int j = 0; j < 8; ++j) { int idx = base + j; if (idx < n) s += deg[idx]; }
    lds[t] = s; __syncthreads();
    for (int off = SCAN_BLK / 2; off; off >>= 1) {
        if (t < off) lds[t] += lds[t + off];
        __syncthreads();
    }
    if (t == 0) partial[b] = lds[0];
}

// --- scan pass B: serial exclusive scan of block sums (nb ~ 49) ---
__global__ void scan_spine(int* __restrict__ partial, int nb, int* __restrict__ off_end) {
    if (threadIdx.x == 0 && blockIdx.x == 0) {
        int run = 0;
        for (int i = 0; i < nb; ++i) { int v = partial[i]; partial[i] = run; run += v; }
        off_end[0] = run;
    }
}

// --- scan pass C: final exclusive scan; writes off[], cursor[], dinv[] ---
__global__ void scan_final(const int* __restrict__ deg, const int* __restrict__ partial,
                           int* __restrict__ off, int* __restrict__ cursor,
                           float* __restrict__ dinv, int n) {
    __shared__ int lds[SCAN_BLK];
    int b = blockIdx.x, t = threadIdx.x;
    int base = b * SCAN_CHUNK + t * 8;
    int v[8]; int s = 0;
#pragma unroll
    for (int j = 0; j < 8; ++j) { int idx = base + j; v[j] = (idx < n) ? deg[idx] : 0; s += v[j]; }
    lds[t] = s; __syncthreads();
    for (int o = 1; o < SCAN_BLK; o <<= 1) {
        int y = (t >= o) ? lds[t - o] : 0;
        __syncthreads();
        if (t >= o) lds[t] += y;
        __syncthreads();
    }
    int run = partial[b] + lds[t] - s;
#pragma unroll
    for (int j = 0; j < 8; ++j) {
        int idx = base + j;
        if (idx < n) {
            off[idx] = run; cursor[idx] = run;
            dinv[idx] = rsqrtf((float)v[j] + 1.0f);   // +1 self-loop
        }
        run += v[j];
    }
}

// --- CSR fill: csr[cursor[dst]++] = src ---
__global__ void fill_kernel(const int* __restrict__ src, const int* __restrict__ dst,
                            int* __restrict__ cursor, int* __restrict__ csr, int e) {
    int i = blockIdx.x * blockDim.x + threadIdx.x;
    if (i < e) {
        int pos = atomicAdd(&cursor[dst[i]], 1);
        csr[pos] = src[i];
    }
}

// --- small GEMM: out[n,64] = (A[n,K] @ W[K,64]) * dinv[row] ---
template<int K>
__global__ void gemm_kernel(const float* __restrict__ A, const float* __restrict__ W,
                            const float* __restrict__ dinv, float* __restrict__ out, int n) {
    __shared__ float Ws[K * 64];
    for (int i = threadIdx.x; i < K * 64; i += blockDim.x) Ws[i] = W[i];
    __syncthreads();
    int row  = blockIdx.x * (blockDim.x >> 6) + (threadIdx.x >> 6);
    int lane = threadIdx.x & 63;
    if (row >= n) return;
    const float4* ar = reinterpret_cast<const float4*>(A + (size_t)row * K);
    float acc = 0.f;
#pragma unroll
    for (int k4 = 0; k4 < K / 4; ++k4) {
        float4 av = ar[k4];
        acc = fmaf(av.x, Ws[(k4 * 4 + 0) * 64 + lane], acc);
        acc = fmaf(av.y, Ws[(k4 * 4 + 1) * 64 + lane], acc);
        acc = fmaf(av.z, Ws[(k4 * 4 + 2) * 64 + lane], acc);
        acc = fmaf(av.w, Ws[(k4 * 4 + 3) * 64 + lane], acc);
    }
    out[(size_t)row * 64 + lane] = acc * dinv[row];
}

// --- gather aggregation: one wave per dst node, lane = feature ---
// 8 independent accumulator chains -> 8 outstanding row loads per wave.
// Neighbor indices loaded 64-at-a-time coalesced, broadcast via __shfl.
template<bool POOL>
__global__ void gather_kernel(const int* __restrict__ off, const int* __restrict__ csr,
                              const float* __restrict__ hws, const float* __restrict__ dinv,
                              const float* __restrict__ b, const int* __restrict__ batch,
                              float* __restrict__ hout, float* __restrict__ pooled,
                              float* __restrict__ cnt, int n) {
    int d = blockIdx.x * (blockDim.x >> 6) + (threadIdx.x >> 6);
    int lane = threadIdx.x & 63;
    if (d >= n) return;
    int beg = off[d], end = off[d + 1];
    float acc[8];
#pragma unroll
    for (int j = 0; j < 8; ++j) acc[j] = 0.f;

    for (int base = beg; base < end; base += 64) {
        int m = end - base; if (m > 64) m = 64;
        int myidx = (lane < m) ? csr[base + lane] : 0;
        int i = 0;
        for (; i + 8 <= m; i += 8) {
#pragma unroll
            for (int j = 0; j < 8; ++j) {
                int s = __shfl(myidx, i + j);
                acc[j] += hws[(size_t)s * 64 + lane];
            }
        }
        for (; i < m; ++i) {
            int s = __shfl(myidx, i);
            acc[i & 7] += hws[(size_t)s * 64 + lane];
        }
    }
    float tot = ((acc[0] + acc[1]) + (acc[2] + acc[3])) +
                ((acc[4] + acc[5]) + (acc[6] + acc[7]));
    float v = (tot + hws[(size_t)d * 64 + lane]) * dinv[d] + b[lane];
    v = fmaxf(v, 0.f);
    if (POOL) {
        int g = batch[d];
        atomicAdd(&pooled[(size_t)g * 64 + lane], v);
        if (lane == 0) atomicAdd(&cnt[g], 1.0f);
    } else {
        hout[(size_t)d * 64 + lane] = v;
    }
}

// --- per-graph head: out[g] = dot(pooled[g]/max(cnt,1), Wfc) + bfc ---
__global__ void final_kernel(const float* __restrict__ pooled, const float* __restrict__ cnt,
                             const float* __restrict__ Wfc, const float* __restrict__ bfc,
                             float* __restrict__ out) {
    int g = blockIdx.x;
    int lane = threadIdx.x;  // block = 64 = 1 wave
    float c = fmaxf(cnt[g], 1.0f);
    float v = (pooled[(size_t)g * 64 + lane] / c) * Wfc[lane];
#pragma unroll
    for (int off = 32; off; off >>= 1) v += __shfl_down(v, off);
    if (lane == 0) out[g] = v + bfc[0];
}

extern "C" void kernel_launch(void* const* d_in, const int* in_sizes, int n_in,
                              void* d_out, int out_size, void* d_ws, size_t ws_size,
                              hipStream_t stream) {
    const float* x    = (const float*)d_in[0];
    const int*   ei   = (const int*)d_in[1];
    const int*   batch= (const int*)d_in[2];
    const float* W1   = (const float*)d_in[3];
    const float* b1   = (const float*)d_in[4];
    const float* W2   = (const float*)d_in[5];
    const float* b2   = (const float*)d_in[6];
    const float* Wfc  = (const float*)d_in[7];
    const float* bfc  = (const float*)d_in[8];
    float* out = (float*)d_out;

    const int n = in_sizes[0] / F_IN;   // 100000
    const int e = in_sizes[1] / 2;      // 3200000
    const int* srcp = ei;
    const int* dstp = ei + e;

    size_t nAl = ((size_t)n + 256) & ~(size_t)255;
    int*   deg     = (int*)d_ws;
    int*   off     = deg + nAl;
    int*   cursor  = off + nAl;
    int*   partial = cursor + nAl;
    float* dinv    = (float*)(partial + 256);
    int*   csr     = (int*)(dinv + nAl);
    size_t eAl     = ((size_t)e + 255) & ~(size_t)255;
    float* hws     = (float*)(csr + eAl);
    float* h1      = hws + (size_t)n * 64;
    float* pooled  = h1 + (size_t)n * 64;
    float* cnt     = pooled + (size_t)NUM_GRAPHS * 64;

    const int nb = (n + SCAN_CHUNK - 1) / SCAN_CHUNK;

    // 1. CSR build
    hipMemsetAsync(deg, 0, (size_t)n * sizeof(int), stream);
    hist_kernel<<<(e + 255) / 256, 256, 0, stream>>>(dstp, deg, e);
    scan_partial<<<nb, SCAN_BLK, 0, stream>>>(deg, partial, n);
    scan_spine<<<1, 64, 0, stream>>>(partial, nb, &off[n]);
    scan_final<<<nb, SCAN_BLK, 0, stream>>>(deg, partial, off, cursor, dinv, n);
    fill_kernel<<<(e + 255) / 256, 256, 0, stream>>>(srcp, dstp, cursor, csr, e);

    // 2. layer 1
    gemm_kernel<F_IN><<<(n + 3) / 4, 256, 0, stream>>>(x, W1, dinv, hws, n);
    gather_kernel<false><<<(n + 3) / 4, 256, 0, stream>>>(off, csr, hws, dinv, b1, batch,
                                                          h1, nullptr, nullptr, n);

    // 3. layer 2
    gemm_kernel<HDIM><<<(n + 3) / 4, 256, 0, stream>>>(h1, W2, dinv, hws, n);
    hipMemsetAsync(pooled, 0, ((size_t)NUM_GRAPHS * 64 + NUM_GRAPHS) * sizeof(float), stream);
    gather_kernel<true><<<(n + 3) / 4, 256, 0, stream>>>(off, csr, hws, dinv, b2, batch,
                                                         nullptr, pooled, cnt, n);

    // 4. head
    final_kernel<<<NUM_GRAPHS, 64, 0, stream>>>(pooled, cnt, Wfc, bfc, out);
}